// Round 1
// baseline (1254.752 us; speedup 1.0000x reference)
//
#include <hip/hip_runtime.h>
#include <cstdint>
#include <cstddef>

#define NEG_SLOPE 0.2f
#define BN_EPS 1e-5f

// ---------------------------------------------------------------------------
// K1: h0[N,128] = x[N,64] @ W1[64,128]; fused epilogue computes
//     as1[n,head] = sum_c h0[n,head*32+c]*att_src1[head,c]  (att flat over 128)
//     ad1[n,head] = sum_c h0[n,head*32+c]*att_dst1[head,c]
// Block 256 = 2 nodes x 128 cols. n is wave-uniform -> readfirstlane so the
// x-row loads become scalar (s_load) broadcasts.
// ---------------------------------------------------------------------------
__global__ void gemm1_kernel(const float* __restrict__ x,
                             const float* __restrict__ W1,
                             const float* __restrict__ att_s,
                             const float* __restrict__ att_d,
                             float* __restrict__ h0,
                             float* __restrict__ as1,
                             float* __restrict__ ad1,
                             int N) {
    int gid = blockIdx.x * 256 + threadIdx.x;
    int c = gid & 127;
    int n = __builtin_amdgcn_readfirstlane(gid >> 7);
    if (n >= N) return;
    const float* __restrict__ xr = x + (size_t)n * 64;
    float acc = 0.f;
#pragma unroll
    for (int k = 0; k < 64; ++k) {
        acc += xr[k] * W1[k * 128 + c];
    }
    h0[(size_t)n * 128 + c] = acc;
    float s = acc * att_s[c];
    float d = acc * att_d[c];
    // reduce over the 32 lanes of one head (xor masks <=16 stay in-group)
#pragma unroll
    for (int off = 16; off >= 1; off >>= 1) {
        s += __shfl_xor(s, off);
        d += __shfl_xor(d, off);
    }
    if ((threadIdx.x & 31) == 0) {
        int head = c >> 5;
        as1[(size_t)n * 4 + head] = s;
        ad1[(size_t)n * 4 + head] = d;
    }
}

// ---------------------------------------------------------------------------
// K2: layer-1 edge pass (one block of 128 threads per edge, incl self-loops).
//     w = exp(leaky_relu(as1[src,h] + ad1[dst,h]))
//     acc1[dst, c] += w * h0[src, c]       (atomic)
//     den1[dst, h] += w                    (atomic, 1 lane per head)
// Normalization folded out: out = acc1/(den1+eps) done in K3.
// ---------------------------------------------------------------------------
__global__ void edge_pass1_kernel(const int* __restrict__ ei, int E,
                                  const float* __restrict__ h0,
                                  const float* __restrict__ as1,
                                  const float* __restrict__ ad1,
                                  float* __restrict__ acc1,
                                  float* __restrict__ den1) {
    int e = blockIdx.x;
    int c = threadIdx.x;            // 0..127
    int src, dst;
    if (e < E) { src = ei[e]; dst = ei[E + e]; }
    else       { src = e - E; dst = src; }
    int head = c >> 5;
    float logit = as1[(size_t)src * 4 + head] + ad1[(size_t)dst * 4 + head];
    float l = logit > 0.f ? logit : NEG_SLOPE * logit;
    float w = __expf(l);
    float hv = h0[(size_t)src * 128 + c];
    atomicAdd(&acc1[(size_t)dst * 128 + c], w * hv);
    if ((c & 31) == 0) {
        atomicAdd(&den1[(size_t)dst * 4 + head], w);
    }
}

// ---------------------------------------------------------------------------
// K3: per-node finalize of layer 1 + layer-2 linear.
//     v = acc1/(den1+1e-16) + b1 -> BN(eval) -> ELU -> h2[n] = sum_c v*W2[c]
// h_post is never materialized (layer 2 only needs scalar h2[src]).
// Block 128 = one node.
// ---------------------------------------------------------------------------
__global__ void node_pass_kernel(const float* __restrict__ acc1,
                                 const float* __restrict__ den1,
                                 const float* __restrict__ b1,
                                 const float* __restrict__ bn_gamma,
                                 const float* __restrict__ bn_beta,
                                 const float* __restrict__ bn_mean,
                                 const float* __restrict__ bn_var,
                                 const float* __restrict__ W2,
                                 float* __restrict__ h2) {
    int n = blockIdx.x;
    int c = threadIdx.x;            // 0..127
    float v = acc1[(size_t)n * 128 + c] / (den1[(size_t)n * 4 + (c >> 5)] + 1e-16f)
              + b1[c];
    v = (v - bn_mean[c]) * rsqrtf(bn_var[c] + BN_EPS) * bn_gamma[c] + bn_beta[c];
    v = v > 0.f ? v : expm1f(v);    // ELU (alpha=1)
    float t = v * W2[c];
#pragma unroll
    for (int off = 32; off >= 1; off >>= 1) t += __shfl_xor(t, off);
    __shared__ float red[2];
    if ((threadIdx.x & 63) == 0) red[threadIdx.x >> 6] = t;
    __syncthreads();
    if (threadIdx.x == 0) h2[n] = red[0] + red[1];
}

// ---------------------------------------------------------------------------
// K4: layer-2 edge pass, one thread per edge (scalar head).
// ---------------------------------------------------------------------------
__global__ void edge_pass2_kernel(const int* __restrict__ ei, int E, int N,
                                  const float* __restrict__ h2,
                                  const float* __restrict__ att_s2,
                                  const float* __restrict__ att_d2,
                                  float* __restrict__ num2,
                                  float* __restrict__ den2) {
    int i = blockIdx.x * 256 + threadIdx.x;
    int T = E + N;
    if (i >= T) return;
    int src, dst;
    if (i < E) { src = ei[i]; dst = ei[E + i]; }
    else       { src = i - E; dst = src; }
    float hs = h2[src];
    float hd = h2[dst];
    float logit = hs * att_s2[0] + hd * att_d2[0];
    float l = logit > 0.f ? logit : NEG_SLOPE * logit;
    float w = __expf(l);
    atomicAdd(&num2[dst], w * hs);
    atomicAdd(&den2[dst], w);
}

// ---------------------------------------------------------------------------
// K5: final output.
// ---------------------------------------------------------------------------
__global__ void out_kernel(const float* __restrict__ num2,
                           const float* __restrict__ den2,
                           const float* __restrict__ b2,
                           float* __restrict__ out, int N) {
    int n = blockIdx.x * 256 + threadIdx.x;
    if (n < N) out[n] = num2[n] / (den2[n] + 1e-16f) + b2[0];
}

extern "C" void kernel_launch(void* const* d_in, const int* in_sizes, int n_in,
                              void* d_out, int out_size, void* d_ws, size_t ws_size,
                              hipStream_t stream) {
    const float* x     = (const float*)d_in[0];
    const int*   ei    = (const int*)  d_in[1];
    const float* W1    = (const float*)d_in[2];
    const float* atts1 = (const float*)d_in[3];
    const float* attd1 = (const float*)d_in[4];
    const float* b1    = (const float*)d_in[5];
    const float* W2    = (const float*)d_in[6];
    const float* atts2 = (const float*)d_in[7];
    const float* attd2 = (const float*)d_in[8];
    const float* b2    = (const float*)d_in[9];
    const float* bn_g  = (const float*)d_in[10];
    const float* bn_b  = (const float*)d_in[11];
    const float* bn_m  = (const float*)d_in[12];
    const float* bn_v  = (const float*)d_in[13];

    const int N = in_sizes[0] / 64;     // 100000
    const int E = in_sizes[1] / 2;      // 1600000
    const int T = E + N;                // edges + self-loops

    // workspace layout (floats):
    //   h0[N*128] | as1[N*4] | ad1[N*4] | h2[N] | acc1[N*128] | den1[N*4] | num2[N] | den2[N]
    float* ws   = (float*)d_ws;
    float* h0   = ws;
    float* as1  = h0  + (size_t)N * 128;
    float* ad1  = as1 + (size_t)N * 4;
    float* h2   = ad1 + (size_t)N * 4;
    float* acc1 = h2  + (size_t)N;
    float* den1 = acc1 + (size_t)N * 128;
    float* num2 = den1 + (size_t)N * 4;
    float* den2 = num2 + (size_t)N;

    // zero the accumulator region (acc1|den1|num2|den2 are contiguous)
    size_t zero_bytes = (size_t)N * (128 + 4 + 1 + 1) * sizeof(float);
    hipMemsetAsync(acc1, 0, zero_bytes, stream);

    gemm1_kernel<<<(N * 128 + 255) / 256, 256, 0, stream>>>(
        x, W1, atts1, attd1, h0, as1, ad1, N);

    edge_pass1_kernel<<<T, 128, 0, stream>>>(ei, E, h0, as1, ad1, acc1, den1);

    node_pass_kernel<<<N, 128, 0, stream>>>(
        acc1, den1, b1, bn_g, bn_b, bn_m, bn_v, W2, h2);

    edge_pass2_kernel<<<(T + 255) / 256, 256, 0, stream>>>(
        ei, E, N, h2, atts2, attd2, num2, den2);

    out_kernel<<<(N + 255) / 256, 256, 0, stream>>>(num2, den2, b2, (float*)d_out, N);
}

// Round 2
// 637.761 us; speedup vs baseline: 1.9674x; 1.9674x over previous
//
#include <hip/hip_runtime.h>
#include <cstdint>
#include <cstddef>

#define NEG_SLOPE 0.2f
#define BN_EPS 1e-5f

// ---------------------------------------------------------------------------
// K1: h0[N,128] = x[N,64] @ W1[64,128]; fused epilogue computes per-node
//     attention terms as1[n,head], ad1[n,head] via 32-lane shuffle reduce.
// ---------------------------------------------------------------------------
__global__ void gemm1_kernel(const float* __restrict__ x,
                             const float* __restrict__ W1,
                             const float* __restrict__ att_s,
                             const float* __restrict__ att_d,
                             float* __restrict__ h0,
                             float* __restrict__ as1,
                             float* __restrict__ ad1,
                             int N) {
    int gid = blockIdx.x * 256 + threadIdx.x;
    int c = gid & 127;
    int n = __builtin_amdgcn_readfirstlane(gid >> 7);
    if (n >= N) return;
    const float* __restrict__ xr = x + (size_t)n * 64;
    float acc = 0.f;
#pragma unroll
    for (int k = 0; k < 64; ++k) {
        acc += xr[k] * W1[k * 128 + c];
    }
    h0[(size_t)n * 128 + c] = acc;
    float s = acc * att_s[c];
    float d = acc * att_d[c];
#pragma unroll
    for (int off = 16; off >= 1; off >>= 1) {
        s += __shfl_xor(s, off);
        d += __shfl_xor(d, off);
    }
    if ((threadIdx.x & 31) == 0) {
        int head = c >> 5;
        as1[(size_t)n * 4 + head] = s;
        ad1[(size_t)n * 4 + head] = d;
    }
}

// ---------------------------------------------------------------------------
// CSR build: counts -> exclusive scan (3 kernels) -> scatter.
// Edge list is E real edges + N self-loops (i>=E => src=dst=i-E).
// ---------------------------------------------------------------------------
__global__ void count_kernel(const int* __restrict__ ei, int E, int N,
                             int* __restrict__ counts) {
    int i = blockIdx.x * 256 + threadIdx.x;
    if (i >= E + N) return;
    int dst = (i < E) ? ei[E + i] : (i - E);
    atomicAdd(&counts[dst], 1);
}

// per-256-block reduction of counts -> psum[block]
__global__ void scan1_kernel(const int* __restrict__ counts, int N,
                             int* __restrict__ psum) {
    __shared__ int s[256];
    int tid = threadIdx.x;
    int i = blockIdx.x * 256 + tid;
    s[tid] = (i < N) ? counts[i] : 0;
    __syncthreads();
#pragma unroll
    for (int off = 128; off >= 1; off >>= 1) {
        if (tid < off) s[tid] += s[tid + off];
        __syncthreads();
    }
    if (tid == 0) psum[blockIdx.x] = s[0];
}

// single-block exclusive scan over up to 512 partial sums
__global__ void scan2_kernel(int* __restrict__ psum, int nb) {
    __shared__ int s[512];
    int tid = threadIdx.x;
    int v = (tid < nb) ? psum[tid] : 0;
    s[tid] = v;
    __syncthreads();
    for (int off = 1; off < 512; off <<= 1) {
        int t = (tid >= off) ? s[tid - off] : 0;
        __syncthreads();
        s[tid] += t;
        __syncthreads();
    }
    if (tid < nb) psum[tid] = s[tid] - v;   // exclusive
}

// local exclusive scan within each 256-block + block offset -> row_ptr, cursor
__global__ void scan3_kernel(const int* __restrict__ counts, int N, int T,
                             const int* __restrict__ psum,
                             int* __restrict__ row_ptr,
                             int* __restrict__ cursor) {
    __shared__ int s[256];
    int tid = threadIdx.x;
    int i = blockIdx.x * 256 + tid;
    int v = (i < N) ? counts[i] : 0;
    s[tid] = v;
    __syncthreads();
    for (int off = 1; off < 256; off <<= 1) {
        int t = (tid >= off) ? s[tid - off] : 0;
        __syncthreads();
        s[tid] += t;
        __syncthreads();
    }
    if (i < N) {
        int excl = s[tid] - v + psum[blockIdx.x];
        row_ptr[i] = excl;
        cursor[i]  = excl;
    }
    if (i == 0) row_ptr[N] = T;
}

__global__ void scatter_kernel(const int* __restrict__ ei, int E, int N,
                               int* __restrict__ cursor,
                               int* __restrict__ csr_src) {
    int i = blockIdx.x * 256 + threadIdx.x;
    if (i >= E + N) return;
    int src, dst;
    if (i < E) { src = ei[i]; dst = ei[E + i]; }
    else       { src = i - E; dst = src; }
    int pos = atomicAdd(&cursor[dst], 1);
    csr_src[pos] = src;
}

// ---------------------------------------------------------------------------
// K6: layer-1 gather + finalize. One 128-thread block per dst node; each
// thread keeps its channel accumulator in a register over the node's
// in-edges, then normalize + b1 + BN + ELU + dot(W2) -> h2[n].
// acc1/den1 are never materialized.
// ---------------------------------------------------------------------------
__global__ void gather1_kernel(const int* __restrict__ row_ptr,
                               const int* __restrict__ csr_src,
                               const float* __restrict__ h0,
                               const float* __restrict__ as1,
                               const float* __restrict__ ad1,
                               const float* __restrict__ b1,
                               const float* __restrict__ bn_gamma,
                               const float* __restrict__ bn_beta,
                               const float* __restrict__ bn_mean,
                               const float* __restrict__ bn_var,
                               const float* __restrict__ W2,
                               float* __restrict__ h2) {
    int n = blockIdx.x;
    int c = threadIdx.x;            // 0..127
    int head = c >> 5;
    int beg = row_ptr[n];
    int end = row_ptr[n + 1];
    float ad = ad1[(size_t)n * 4 + head];
    float acc = 0.f, den = 0.f;
    // 2-stage pipeline: prefetch next src index to break the dependency chain
    int src_next = (beg < end) ? csr_src[beg] : 0;
    for (int j = beg; j < end; ++j) {
        int src = src_next;
        if (j + 1 < end) src_next = csr_src[j + 1];
        float as = as1[(size_t)src * 4 + head];
        float lg = as + ad;
        float l = lg > 0.f ? lg : NEG_SLOPE * lg;
        float w = __expf(l);
        acc += w * h0[(size_t)src * 128 + c];
        den += w;
    }
    float v = acc / (den + 1e-16f) + b1[c];
    v = (v - bn_mean[c]) * rsqrtf(bn_var[c] + BN_EPS) * bn_gamma[c] + bn_beta[c];
    v = v > 0.f ? v : expm1f(v);    // ELU (alpha=1)
    float t = v * W2[c];
#pragma unroll
    for (int off = 32; off >= 1; off >>= 1) t += __shfl_xor(t, off);
    __shared__ float red[2];
    if ((threadIdx.x & 63) == 0) red[threadIdx.x >> 6] = t;
    __syncthreads();
    if (threadIdx.x == 0) h2[n] = red[0] + red[1];
}

// ---------------------------------------------------------------------------
// K7: layer-2 gather. One 64-lane wave per dst node (block 256 = 4 nodes);
// lanes stride the node's in-edges, shuffle-reduce num/den, write out.
// ---------------------------------------------------------------------------
__global__ void gather2_kernel(const int* __restrict__ row_ptr,
                               const int* __restrict__ csr_src,
                               const float* __restrict__ h2,
                               const float* __restrict__ att_s2,
                               const float* __restrict__ att_d2,
                               const float* __restrict__ b2,
                               float* __restrict__ out, int N) {
    int n = blockIdx.x * 4 + (threadIdx.x >> 6);
    if (n >= N) return;
    int lane = threadIdx.x & 63;
    int beg = row_ptr[n];
    int end = row_ptr[n + 1];
    float a_s = att_s2[0];
    float a_d = att_d2[0];
    float hd = h2[n];
    float num = 0.f, den = 0.f;
    for (int j = beg + lane; j < end; j += 64) {
        int src = csr_src[j];
        float hs = h2[src];
        float lg = hs * a_s + hd * a_d;
        float l = lg > 0.f ? lg : NEG_SLOPE * lg;
        float w = __expf(l);
        num += w * hs;
        den += w;
    }
#pragma unroll
    for (int off = 32; off >= 1; off >>= 1) {
        num += __shfl_xor(num, off);
        den += __shfl_xor(den, off);
    }
    if (lane == 0) out[n] = num / (den + 1e-16f) + b2[0];
}

extern "C" void kernel_launch(void* const* d_in, const int* in_sizes, int n_in,
                              void* d_out, int out_size, void* d_ws, size_t ws_size,
                              hipStream_t stream) {
    const float* x     = (const float*)d_in[0];
    const int*   ei    = (const int*)  d_in[1];
    const float* W1    = (const float*)d_in[2];
    const float* atts1 = (const float*)d_in[3];
    const float* attd1 = (const float*)d_in[4];
    const float* b1    = (const float*)d_in[5];
    const float* W2    = (const float*)d_in[6];
    const float* atts2 = (const float*)d_in[7];
    const float* attd2 = (const float*)d_in[8];
    const float* b2    = (const float*)d_in[9];
    const float* bn_g  = (const float*)d_in[10];
    const float* bn_b  = (const float*)d_in[11];
    const float* bn_m  = (const float*)d_in[12];
    const float* bn_v  = (const float*)d_in[13];

    const int N = in_sizes[0] / 64;     // 100000
    const int E = in_sizes[1] / 2;      // 1600000
    const int T = E + N;                // edges + self-loops
    const int NB = (N + 255) / 256;     // scan blocks (<=512)

    // workspace layout:
    //   h0[N*128] f | as1[4N] f | ad1[4N] f | h2[N] f |
    //   row_ptr[N+1] i | cursor[N] i | counts[N] i | psum[512] i | csr_src[T] i
    float* ws      = (float*)d_ws;
    float* h0      = ws;
    float* as1     = h0  + (size_t)N * 128;
    float* ad1     = as1 + (size_t)N * 4;
    float* h2      = ad1 + (size_t)N * 4;
    int*   row_ptr = (int*)(h2 + (size_t)N);
    int*   cursor  = row_ptr + (size_t)(N + 1);
    int*   counts  = cursor  + (size_t)N;
    int*   psum    = counts  + (size_t)N;
    int*   csr_src = psum    + 512;

    hipMemsetAsync(counts, 0, (size_t)N * sizeof(int), stream);

    // CSR build + GEMM1 (independent; CSR kernels overlap poorly but are small)
    count_kernel<<<(T + 255) / 256, 256, 0, stream>>>(ei, E, N, counts);
    scan1_kernel<<<NB, 256, 0, stream>>>(counts, N, psum);
    scan2_kernel<<<1, 512, 0, stream>>>(psum, NB);
    scan3_kernel<<<NB, 256, 0, stream>>>(counts, N, T, psum, row_ptr, cursor);
    scatter_kernel<<<(T + 255) / 256, 256, 0, stream>>>(ei, E, N, cursor, csr_src);

    gemm1_kernel<<<(N * 128 + 255) / 256, 256, 0, stream>>>(
        x, W1, atts1, attd1, h0, as1, ad1, N);

    gather1_kernel<<<N, 128, 0, stream>>>(
        row_ptr, csr_src, h0, as1, ad1, b1, bn_g, bn_b, bn_m, bn_v, W2, h2);

    gather2_kernel<<<(N + 3) / 4, 256, 0, stream>>>(
        row_ptr, csr_src, h2, atts2, attd2, b2, (float*)d_out, N);
}

// Round 3
// 504.339 us; speedup vs baseline: 2.4879x; 1.2645x over previous
//
#include <hip/hip_runtime.h>
#include <cstdint>
#include <cstddef>

#define NEG_SLOPE 0.2f
#define BN_EPS 1e-5f

// ---------------------------------------------------------------------------
// K1: h0[N,128] = x[N,64] @ W1[64,128], 4 nodes per thread (W1 reuse x4).
// Fused epilogue: as1[n,head], ad1[n,head] via 32-lane shuffle reduce.
// Block 256 = 2 wave-pairs x 128 cols; 8 nodes per block.
// ---------------------------------------------------------------------------
__global__ void gemm1_kernel(const float* __restrict__ x,
                             const float* __restrict__ W1,
                             const float* __restrict__ att_s,
                             const float* __restrict__ att_d,
                             float* __restrict__ h0,
                             float* __restrict__ as1,
                             float* __restrict__ ad1,
                             int N) {
    int c = threadIdx.x & 127;
    int pair = __builtin_amdgcn_readfirstlane(threadIdx.x >> 7);
    int n0 = (blockIdx.x * 2 + pair) * 4;
    if (n0 >= N) return;
    float acc[4] = {0.f, 0.f, 0.f, 0.f};
    const float* __restrict__ xr = x + (size_t)n0 * 64;
    int nn = N - n0; if (nn > 4) nn = 4;   // N%8==0 in practice; generic guard
    if (nn == 4) {
#pragma unroll
        for (int k = 0; k < 64; ++k) {
            float w = W1[k * 128 + c];
            acc[0] = fmaf(xr[k],       w, acc[0]);
            acc[1] = fmaf(xr[64 + k],  w, acc[1]);
            acc[2] = fmaf(xr[128 + k], w, acc[2]);
            acc[3] = fmaf(xr[192 + k], w, acc[3]);
        }
    } else {
        for (int i = 0; i < nn; ++i)
            for (int k = 0; k < 64; ++k)
                acc[i] = fmaf(xr[i * 64 + k], W1[k * 128 + c], acc[i]);
    }
    float asc = att_s[c], adc = att_d[c];
    int head = c >> 5;
#pragma unroll
    for (int i = 0; i < 4; ++i) {
        if (i >= nn) break;
        int n = n0 + i;
        h0[(size_t)n * 128 + c] = acc[i];
        float s = acc[i] * asc;
        float d = acc[i] * adc;
#pragma unroll
        for (int off = 16; off >= 1; off >>= 1) {
            s += __shfl_xor(s, off);
            d += __shfl_xor(d, off);
        }
        if ((threadIdx.x & 31) == 0) {
            as1[(size_t)n * 4 + head] = s;
            ad1[(size_t)n * 4 + head] = d;
        }
    }
}

// ---------------------------------------------------------------------------
// CSR build: counts -> exclusive scan (3 kernels) -> scatter.
// Edge list is E real edges + N self-loops (i>=E => src=dst=i-E).
// ---------------------------------------------------------------------------
__global__ void count_kernel(const int* __restrict__ ei, int E, int N,
                             int* __restrict__ counts) {
    int i = blockIdx.x * 256 + threadIdx.x;
    if (i >= E + N) return;
    int dst = (i < E) ? ei[E + i] : (i - E);
    atomicAdd(&counts[dst], 1);
}

__global__ void scan1_kernel(const int* __restrict__ counts, int N,
                             int* __restrict__ psum) {
    __shared__ int s[256];
    int tid = threadIdx.x;
    int i = blockIdx.x * 256 + tid;
    s[tid] = (i < N) ? counts[i] : 0;
    __syncthreads();
#pragma unroll
    for (int off = 128; off >= 1; off >>= 1) {
        if (tid < off) s[tid] += s[tid + off];
        __syncthreads();
    }
    if (tid == 0) psum[blockIdx.x] = s[0];
}

__global__ void scan2_kernel(int* __restrict__ psum, int nb) {
    __shared__ int s[512];
    int tid = threadIdx.x;
    int v = (tid < nb) ? psum[tid] : 0;
    s[tid] = v;
    __syncthreads();
    for (int off = 1; off < 512; off <<= 1) {
        int t = (tid >= off) ? s[tid - off] : 0;
        __syncthreads();
        s[tid] += t;
        __syncthreads();
    }
    if (tid < nb) psum[tid] = s[tid] - v;   // exclusive
}

__global__ void scan3_kernel(const int* __restrict__ counts, int N, int T,
                             const int* __restrict__ psum,
                             int* __restrict__ row_ptr,
                             int* __restrict__ cursor) {
    __shared__ int s[256];
    int tid = threadIdx.x;
    int i = blockIdx.x * 256 + tid;
    int v = (i < N) ? counts[i] : 0;
    s[tid] = v;
    __syncthreads();
    for (int off = 1; off < 256; off <<= 1) {
        int t = (tid >= off) ? s[tid - off] : 0;
        __syncthreads();
        s[tid] += t;
        __syncthreads();
    }
    if (i < N) {
        int excl = s[tid] - v + psum[blockIdx.x];
        row_ptr[i] = excl;
        cursor[i]  = excl;
    }
    if (i == 0) row_ptr[N] = T;
}

__global__ void scatter_kernel(const int* __restrict__ ei, int E, int N,
                               int* __restrict__ cursor,
                               int* __restrict__ csr_src) {
    int i = blockIdx.x * 256 + threadIdx.x;
    if (i >= E + N) return;
    int src, dst;
    if (i < E) { src = ei[i]; dst = ei[E + i]; }
    else       { src = i - E; dst = src; }
    int pos = atomicAdd(&cursor[dst], 1);
    csr_src[pos] = src;
}

// ---------------------------------------------------------------------------
// K6: layer-1 gather + finalize. ONE WAVE per dst node (block 256 = 4 nodes).
// Wave splits into 2x32-lane groups; group g walks edges beg+g, beg+g+2,...
// Each lane loads a float4 of the 512B h0 row (32 lanes x 16B). Accumulators
// live in registers; groups combine via shfl_xor(32); then normalize + b1 +
// BN + ELU + dot(W2) -> h2[n]. acc1/den1 never materialized.
// ---------------------------------------------------------------------------
__global__ void gather1_kernel(const int* __restrict__ row_ptr,
                               const int* __restrict__ csr_src,
                               const float4* __restrict__ h0,
                               const float* __restrict__ as1,
                               const float* __restrict__ ad1,
                               const float* __restrict__ b1,
                               const float* __restrict__ bn_gamma,
                               const float* __restrict__ bn_beta,
                               const float* __restrict__ bn_mean,
                               const float* __restrict__ bn_var,
                               const float* __restrict__ W2,
                               float* __restrict__ h2, int N) {
    int n = blockIdx.x * 4 + (threadIdx.x >> 6);
    if (n >= N) return;
    int lane = threadIdx.x & 63;
    int sub  = lane & 31;           // float4 index within the 128-ch row
    int grp  = lane >> 5;           // which edge of the pair
    int head = sub >> 3;            // channels 4*sub..4*sub+3 are in this head
    float ad = ad1[(size_t)n * 4 + head];
    int beg = row_ptr[n];
    int end = row_ptr[n + 1];
    float4 acc = make_float4(0.f, 0.f, 0.f, 0.f);
    float den = 0.f;
#pragma unroll 2
    for (int j = beg + grp; j < end; j += 2) {
        int src = csr_src[j];
        float as = as1[(size_t)src * 4 + head];
        float lg = as + ad;
        float l = fmaf(NEG_SLOPE, fminf(lg, 0.f), fmaxf(lg, 0.f));
        float w = __expf(l);
        float4 hv = h0[(size_t)src * 32 + sub];
        acc.x = fmaf(w, hv.x, acc.x);
        acc.y = fmaf(w, hv.y, acc.y);
        acc.z = fmaf(w, hv.z, acc.z);
        acc.w = fmaf(w, hv.w, acc.w);
        den += w;
    }
    // combine the two edge-groups (xor 32 reaches the partner lane)
    acc.x += __shfl_xor(acc.x, 32);
    acc.y += __shfl_xor(acc.y, 32);
    acc.z += __shfl_xor(acc.z, 32);
    acc.w += __shfl_xor(acc.w, 32);
    den   += __shfl_xor(den, 32);
    float inv = 1.f / (den + 1e-16f);
    int c = sub * 4;
    float v0 = acc.x * inv + b1[c];
    float v1 = acc.y * inv + b1[c + 1];
    float v2 = acc.z * inv + b1[c + 2];
    float v3 = acc.w * inv + b1[c + 3];
    v0 = (v0 - bn_mean[c])     * rsqrtf(bn_var[c]     + BN_EPS) * bn_gamma[c]     + bn_beta[c];
    v1 = (v1 - bn_mean[c + 1]) * rsqrtf(bn_var[c + 1] + BN_EPS) * bn_gamma[c + 1] + bn_beta[c + 1];
    v2 = (v2 - bn_mean[c + 2]) * rsqrtf(bn_var[c + 2] + BN_EPS) * bn_gamma[c + 2] + bn_beta[c + 2];
    v3 = (v3 - bn_mean[c + 3]) * rsqrtf(bn_var[c + 3] + BN_EPS) * bn_gamma[c + 3] + bn_beta[c + 3];
    v0 = v0 > 0.f ? v0 : expm1f(v0);
    v1 = v1 > 0.f ? v1 : expm1f(v1);
    v2 = v2 > 0.f ? v2 : expm1f(v2);
    v3 = v3 > 0.f ? v3 : expm1f(v3);
    float t = v0 * W2[c] + v1 * W2[c + 1] + v2 * W2[c + 2] + v3 * W2[c + 3];
#pragma unroll
    for (int off = 16; off >= 1; off >>= 1) t += __shfl_xor(t, off);
    if (lane == 0) h2[n] = t;
}

// ---------------------------------------------------------------------------
// K7: layer-2 gather. One 64-lane wave per dst node (block 256 = 4 nodes).
// ---------------------------------------------------------------------------
__global__ void gather2_kernel(const int* __restrict__ row_ptr,
                               const int* __restrict__ csr_src,
                               const float* __restrict__ h2,
                               const float* __restrict__ att_s2,
                               const float* __restrict__ att_d2,
                               const float* __restrict__ b2,
                               float* __restrict__ out, int N) {
    int n = blockIdx.x * 4 + (threadIdx.x >> 6);
    if (n >= N) return;
    int lane = threadIdx.x & 63;
    int beg = row_ptr[n];
    int end = row_ptr[n + 1];
    float a_s = att_s2[0];
    float a_d = att_d2[0];
    float hd = h2[n];
    float num = 0.f, den = 0.f;
    for (int j = beg + lane; j < end; j += 64) {
        int src = csr_src[j];
        float hs = h2[src];
        float lg = hs * a_s + hd * a_d;
        float l = fmaf(NEG_SLOPE, fminf(lg, 0.f), fmaxf(lg, 0.f));
        float w = __expf(l);
        num += w * hs;
        den += w;
    }
#pragma unroll
    for (int off = 32; off >= 1; off >>= 1) {
        num += __shfl_xor(num, off);
        den += __shfl_xor(den, off);
    }
    if (lane == 0) out[n] = num / (den + 1e-16f) + b2[0];
}

extern "C" void kernel_launch(void* const* d_in, const int* in_sizes, int n_in,
                              void* d_out, int out_size, void* d_ws, size_t ws_size,
                              hipStream_t stream) {
    const float* x     = (const float*)d_in[0];
    const int*   ei    = (const int*)  d_in[1];
    const float* W1    = (const float*)d_in[2];
    const float* atts1 = (const float*)d_in[3];
    const float* attd1 = (const float*)d_in[4];
    const float* b1    = (const float*)d_in[5];
    const float* W2    = (const float*)d_in[6];
    const float* atts2 = (const float*)d_in[7];
    const float* attd2 = (const float*)d_in[8];
    const float* b2    = (const float*)d_in[9];
    const float* bn_g  = (const float*)d_in[10];
    const float* bn_b  = (const float*)d_in[11];
    const float* bn_m  = (const float*)d_in[12];
    const float* bn_v  = (const float*)d_in[13];

    const int N = in_sizes[0] / 64;     // 100000
    const int E = in_sizes[1] / 2;      // 1600000
    const int T = E + N;                // edges + self-loops
    const int NB = (N + 255) / 256;     // scan blocks (<=512)

    // workspace layout:
    //   h0[N*128] f | as1[4N] f | ad1[4N] f | h2[N] f |
    //   row_ptr[N+1] i | cursor[N] i | counts[N] i | psum[512] i | csr_src[T] i
    float* ws      = (float*)d_ws;
    float* h0      = ws;
    float* as1     = h0  + (size_t)N * 128;
    float* ad1     = as1 + (size_t)N * 4;
    float* h2      = ad1 + (size_t)N * 4;
    int*   row_ptr = (int*)(h2 + (size_t)N);
    int*   cursor  = row_ptr + (size_t)(N + 1);
    int*   counts  = cursor  + (size_t)N;
    int*   psum    = counts  + (size_t)N;
    int*   csr_src = psum    + 512;

    hipMemsetAsync(counts, 0, (size_t)N * sizeof(int), stream);

    count_kernel<<<(T + 255) / 256, 256, 0, stream>>>(ei, E, N, counts);
    scan1_kernel<<<NB, 256, 0, stream>>>(counts, N, psum);
    scan2_kernel<<<1, 512, 0, stream>>>(psum, NB);
    scan3_kernel<<<NB, 256, 0, stream>>>(counts, N, T, psum, row_ptr, cursor);
    scatter_kernel<<<(T + 255) / 256, 256, 0, stream>>>(ei, E, N, cursor, csr_src);

    gemm1_kernel<<<(N + 7) / 8, 256, 0, stream>>>(
        x, W1, atts1, attd1, h0, as1, ad1, N);

    gather1_kernel<<<(N + 3) / 4, 256, 0, stream>>>(
        row_ptr, csr_src, (const float4*)h0, as1, ad1, b1, bn_g, bn_b, bn_m, bn_v,
        W2, h2, N);

    gather2_kernel<<<(N + 3) / 4, 256, 0, stream>>>(
        row_ptr, csr_src, h2, atts2, attd2, b2, (float*)d_out, N);
}

// Round 4
// 464.367 us; speedup vs baseline: 2.7021x; 1.0861x over previous
//
#include <hip/hip_runtime.h>
#include <cstdint>
#include <cstddef>

#define NEG_SLOPE 0.2f
#define BN_EPS 1e-5f

typedef _Float16 half4 __attribute__((ext_vector_type(4)));

// ---------------------------------------------------------------------------
// K1: h0[N,128] = x[N,64] @ W1[64,128], 4 nodes per thread (W1 reuse x4).
// h0 stored as fp16 (halves gather1 traffic; fp32 math throughout).
// Fused epilogue: as1[n,head], ad1[n,head] via 32-lane shuffle reduce.
// ---------------------------------------------------------------------------
__global__ void gemm1_kernel(const float* __restrict__ x,
                             const float* __restrict__ W1,
                             const float* __restrict__ att_s,
                             const float* __restrict__ att_d,
                             _Float16* __restrict__ h0,
                             float* __restrict__ as1,
                             float* __restrict__ ad1,
                             int N) {
    int c = threadIdx.x & 127;
    int pair = __builtin_amdgcn_readfirstlane(threadIdx.x >> 7);
    int n0 = (blockIdx.x * 2 + pair) * 4;
    if (n0 >= N) return;
    float acc[4] = {0.f, 0.f, 0.f, 0.f};
    const float* __restrict__ xr = x + (size_t)n0 * 64;
    int nn = N - n0; if (nn > 4) nn = 4;
    if (nn == 4) {
#pragma unroll
        for (int k = 0; k < 64; ++k) {
            float w = W1[k * 128 + c];
            acc[0] = fmaf(xr[k],       w, acc[0]);
            acc[1] = fmaf(xr[64 + k],  w, acc[1]);
            acc[2] = fmaf(xr[128 + k], w, acc[2]);
            acc[3] = fmaf(xr[192 + k], w, acc[3]);
        }
    } else {
        for (int i = 0; i < nn; ++i)
            for (int k = 0; k < 64; ++k)
                acc[i] = fmaf(xr[i * 64 + k], W1[k * 128 + c], acc[i]);
    }
    float asc = att_s[c], adc = att_d[c];
    int head = c >> 5;
#pragma unroll
    for (int i = 0; i < 4; ++i) {
        if (i >= nn) break;
        int n = n0 + i;
        h0[(size_t)n * 128 + c] = (_Float16)acc[i];
        float s = acc[i] * asc;
        float d = acc[i] * adc;
#pragma unroll
        for (int off = 16; off >= 1; off >>= 1) {
            s += __shfl_xor(s, off);
            d += __shfl_xor(d, off);
        }
        if ((threadIdx.x & 31) == 0) {
            as1[(size_t)n * 4 + head] = s;
            ad1[(size_t)n * 4 + head] = d;
        }
    }
}

// ---------------------------------------------------------------------------
// CSR build: counts -> exclusive scan (3 kernels) -> scatter.
// Edge list is E real edges + N self-loops (i>=E => src=dst=i-E).
// ---------------------------------------------------------------------------
__global__ void count_kernel(const int* __restrict__ ei, int E, int N,
                             int* __restrict__ counts) {
    int i = blockIdx.x * 256 + threadIdx.x;
    if (i >= E + N) return;
    int dst = (i < E) ? ei[E + i] : (i - E);
    atomicAdd(&counts[dst], 1);
}

__global__ void scan1_kernel(const int* __restrict__ counts, int N,
                             int* __restrict__ psum) {
    __shared__ int s[256];
    int tid = threadIdx.x;
    int i = blockIdx.x * 256 + tid;
    s[tid] = (i < N) ? counts[i] : 0;
    __syncthreads();
#pragma unroll
    for (int off = 128; off >= 1; off >>= 1) {
        if (tid < off) s[tid] += s[tid + off];
        __syncthreads();
    }
    if (tid == 0) psum[blockIdx.x] = s[0];
}

__global__ void scan2_kernel(int* __restrict__ psum, int nb) {
    __shared__ int s[512];
    int tid = threadIdx.x;
    int v = (tid < nb) ? psum[tid] : 0;
    s[tid] = v;
    __syncthreads();
    for (int off = 1; off < 512; off <<= 1) {
        int t = (tid >= off) ? s[tid - off] : 0;
        __syncthreads();
        s[tid] += t;
        __syncthreads();
    }
    if (tid < nb) psum[tid] = s[tid] - v;   // exclusive
}

__global__ void scan3_kernel(const int* __restrict__ counts, int N, int T,
                             const int* __restrict__ psum,
                             int* __restrict__ row_ptr,
                             int* __restrict__ cursor) {
    __shared__ int s[256];
    int tid = threadIdx.x;
    int i = blockIdx.x * 256 + tid;
    int v = (i < N) ? counts[i] : 0;
    s[tid] = v;
    __syncthreads();
    for (int off = 1; off < 256; off <<= 1) {
        int t = (tid >= off) ? s[tid - off] : 0;
        __syncthreads();
        s[tid] += t;
        __syncthreads();
    }
    if (i < N) {
        int excl = s[tid] - v + psum[blockIdx.x];
        row_ptr[i] = excl;
        cursor[i]  = excl;
    }
    if (i == 0) row_ptr[N] = T;
}

__global__ void scatter_kernel(const int* __restrict__ ei, int E, int N,
                               int* __restrict__ cursor,
                               int* __restrict__ csr_src) {
    int i = blockIdx.x * 256 + threadIdx.x;
    if (i >= E + N) return;
    int src, dst;
    if (i < E) { src = ei[i]; dst = ei[E + i]; }
    else       { src = i - E; dst = src; }
    int pos = atomicAdd(&cursor[dst], 1);
    csr_src[pos] = src;
}

// ---------------------------------------------------------------------------
// K6: layer-1 gather + finalize. ONE WAVE per dst node (block 256 = 4 nodes).
// Wave splits into 2x32-lane groups; group g walks edges beg+g, beg+g+2,...
// Each lane loads a half4 (8B) of the 256B fp16 h0 row. Accumulators fp32 in
// registers; groups combine via shfl_xor(32); then normalize + b1 + BN + ELU
// + dot(W2) -> h2[n]. acc1/den1 never materialized.
// ---------------------------------------------------------------------------
__global__ void gather1_kernel(const int* __restrict__ row_ptr,
                               const int* __restrict__ csr_src,
                               const half4* __restrict__ h0,
                               const float* __restrict__ as1,
                               const float* __restrict__ ad1,
                               const float* __restrict__ b1,
                               const float* __restrict__ bn_gamma,
                               const float* __restrict__ bn_beta,
                               const float* __restrict__ bn_mean,
                               const float* __restrict__ bn_var,
                               const float* __restrict__ W2,
                               float* __restrict__ h2, int N) {
    int n = blockIdx.x * 4 + (threadIdx.x >> 6);
    if (n >= N) return;
    int lane = threadIdx.x & 63;
    int sub  = lane & 31;           // half4 index within the 128-ch row
    int grp  = lane >> 5;           // which edge of the pair
    int head = sub >> 3;            // channels 4*sub..4*sub+3 are in this head
    float ad = ad1[(size_t)n * 4 + head];
    int beg = row_ptr[n];
    int end = row_ptr[n + 1];
    float4 acc = make_float4(0.f, 0.f, 0.f, 0.f);
    float den = 0.f;
#pragma unroll 2
    for (int j = beg + grp; j < end; j += 2) {
        int src = csr_src[j];
        float as = as1[(size_t)src * 4 + head];
        float lg = as + ad;
        float l = fmaf(NEG_SLOPE, fminf(lg, 0.f), fmaxf(lg, 0.f));
        float w = __expf(l);
        half4 hv = h0[(size_t)src * 32 + sub];
        acc.x = fmaf(w, (float)hv.x, acc.x);
        acc.y = fmaf(w, (float)hv.y, acc.y);
        acc.z = fmaf(w, (float)hv.z, acc.z);
        acc.w = fmaf(w, (float)hv.w, acc.w);
        den += w;
    }
    // combine the two edge-groups (xor 32 reaches the partner lane)
    acc.x += __shfl_xor(acc.x, 32);
    acc.y += __shfl_xor(acc.y, 32);
    acc.z += __shfl_xor(acc.z, 32);
    acc.w += __shfl_xor(acc.w, 32);
    den   += __shfl_xor(den, 32);
    float inv = 1.f / (den + 1e-16f);
    int c = sub * 4;
    float v0 = acc.x * inv + b1[c];
    float v1 = acc.y * inv + b1[c + 1];
    float v2 = acc.z * inv + b1[c + 2];
    float v3 = acc.w * inv + b1[c + 3];
    v0 = (v0 - bn_mean[c])     * rsqrtf(bn_var[c]     + BN_EPS) * bn_gamma[c]     + bn_beta[c];
    v1 = (v1 - bn_mean[c + 1]) * rsqrtf(bn_var[c + 1] + BN_EPS) * bn_gamma[c + 1] + bn_beta[c + 1];
    v2 = (v2 - bn_mean[c + 2]) * rsqrtf(bn_var[c + 2] + BN_EPS) * bn_gamma[c + 2] + bn_beta[c + 2];
    v3 = (v3 - bn_mean[c + 3]) * rsqrtf(bn_var[c + 3] + BN_EPS) * bn_gamma[c + 3] + bn_beta[c + 3];
    v0 = v0 > 0.f ? v0 : expm1f(v0);
    v1 = v1 > 0.f ? v1 : expm1f(v1);
    v2 = v2 > 0.f ? v2 : expm1f(v2);
    v3 = v3 > 0.f ? v3 : expm1f(v3);
    float t = v0 * W2[c] + v1 * W2[c + 1] + v2 * W2[c + 2] + v3 * W2[c + 3];
#pragma unroll
    for (int off = 16; off >= 1; off >>= 1) t += __shfl_xor(t, off);
    if (lane == 0) h2[n] = t;
}

// ---------------------------------------------------------------------------
// K7: layer-2 gather. One 64-lane wave per dst node (block 256 = 4 nodes).
// ---------------------------------------------------------------------------
__global__ void gather2_kernel(const int* __restrict__ row_ptr,
                               const int* __restrict__ csr_src,
                               const float* __restrict__ h2,
                               const float* __restrict__ att_s2,
                               const float* __restrict__ att_d2,
                               const float* __restrict__ b2,
                               float* __restrict__ out, int N) {
    int n = blockIdx.x * 4 + (threadIdx.x >> 6);
    if (n >= N) return;
    int lane = threadIdx.x & 63;
    int beg = row_ptr[n];
    int end = row_ptr[n + 1];
    float a_s = att_s2[0];
    float a_d = att_d2[0];
    float hd = h2[n];
    float num = 0.f, den = 0.f;
    for (int j = beg + lane; j < end; j += 64) {
        int src = csr_src[j];
        float hs = h2[src];
        float lg = hs * a_s + hd * a_d;
        float l = fmaf(NEG_SLOPE, fminf(lg, 0.f), fmaxf(lg, 0.f));
        float w = __expf(l);
        num += w * hs;
        den += w;
    }
#pragma unroll
    for (int off = 32; off >= 1; off >>= 1) {
        num += __shfl_xor(num, off);
        den += __shfl_xor(den, off);
    }
    if (lane == 0) out[n] = num / (den + 1e-16f) + b2[0];
}

extern "C" void kernel_launch(void* const* d_in, const int* in_sizes, int n_in,
                              void* d_out, int out_size, void* d_ws, size_t ws_size,
                              hipStream_t stream) {
    const float* x     = (const float*)d_in[0];
    const int*   ei    = (const int*)  d_in[1];
    const float* W1    = (const float*)d_in[2];
    const float* atts1 = (const float*)d_in[3];
    const float* attd1 = (const float*)d_in[4];
    const float* b1    = (const float*)d_in[5];
    const float* W2    = (const float*)d_in[6];
    const float* atts2 = (const float*)d_in[7];
    const float* attd2 = (const float*)d_in[8];
    const float* b2    = (const float*)d_in[9];
    const float* bn_g  = (const float*)d_in[10];
    const float* bn_b  = (const float*)d_in[11];
    const float* bn_m  = (const float*)d_in[12];
    const float* bn_v  = (const float*)d_in[13];

    const int N = in_sizes[0] / 64;     // 100000
    const int E = in_sizes[1] / 2;      // 1600000
    const int T = E + N;                // edges + self-loops
    const int NB = (N + 255) / 256;     // scan blocks (<=512)

    // workspace layout:
    //   h0[N*128] fp16 | as1[4N] f | ad1[4N] f | h2[N] f |
    //   row_ptr[N+1] i | cursor[N] i | counts[N] i | psum[512] i | csr_src[T] i
    _Float16* h0   = (_Float16*)d_ws;
    float* as1     = (float*)(h0 + (size_t)N * 128);
    float* ad1     = as1 + (size_t)N * 4;
    float* h2      = ad1 + (size_t)N * 4;
    int*   row_ptr = (int*)(h2 + (size_t)N);
    int*   cursor  = row_ptr + (size_t)(N + 1);
    int*   counts  = cursor  + (size_t)N;
    int*   psum    = counts  + (size_t)N;
    int*   csr_src = psum    + 512;

    hipMemsetAsync(counts, 0, (size_t)N * sizeof(int), stream);

    count_kernel<<<(T + 255) / 256, 256, 0, stream>>>(ei, E, N, counts);
    scan1_kernel<<<NB, 256, 0, stream>>>(counts, N, psum);
    scan2_kernel<<<1, 512, 0, stream>>>(psum, NB);
    scan3_kernel<<<NB, 256, 0, stream>>>(counts, N, T, psum, row_ptr, cursor);
    scatter_kernel<<<(T + 255) / 256, 256, 0, stream>>>(ei, E, N, cursor, csr_src);

    gemm1_kernel<<<(N + 7) / 8, 256, 0, stream>>>(
        x, W1, atts1, attd1, h0, as1, ad1, N);

    gather1_kernel<<<(N + 3) / 4, 256, 0, stream>>>(
        row_ptr, csr_src, (const half4*)h0, as1, ad1, b1, bn_g, bn_b, bn_m, bn_v,
        W2, h2, N);

    gather2_kernel<<<(N + 3) / 4, 256, 0, stream>>>(
        row_ptr, csr_src, h2, atts2, attd2, b2, (float*)d_out, N);
}

// Round 5
// 347.309 us; speedup vs baseline: 3.6128x; 1.3370x over previous
//
#include <hip/hip_runtime.h>
#include <cstdint>
#include <cstddef>

#define NEG_SLOPE 0.2f
#define BN_EPS 1e-5f
#define BK_SHIFT 8          // 256 nodes per bucket
#define MAXBK 512           // supports N <= 131072
#define CHUNK 2048          // edges per binning block

typedef _Float16 half4 __attribute__((ext_vector_type(4)));

// ---------------------------------------------------------------------------
// K1: h0[N,128] = x[N,64] @ W1[64,128], 4 nodes per thread (W1 reuse x4).
// h0 stored fp16; fused epilogue computes as1/ad1 via 32-lane shuffle reduce.
// ---------------------------------------------------------------------------
__global__ void gemm1_kernel(const float* __restrict__ x,
                             const float* __restrict__ W1,
                             const float* __restrict__ att_s,
                             const float* __restrict__ att_d,
                             _Float16* __restrict__ h0,
                             float* __restrict__ as1,
                             float* __restrict__ ad1,
                             int N) {
    int c = threadIdx.x & 127;
    int pair = __builtin_amdgcn_readfirstlane(threadIdx.x >> 7);
    int n0 = (blockIdx.x * 2 + pair) * 4;
    if (n0 >= N) return;
    float acc[4] = {0.f, 0.f, 0.f, 0.f};
    const float* __restrict__ xr = x + (size_t)n0 * 64;
    int nn = N - n0; if (nn > 4) nn = 4;
    if (nn == 4) {
#pragma unroll
        for (int k = 0; k < 64; ++k) {
            float w = W1[k * 128 + c];
            acc[0] = fmaf(xr[k],       w, acc[0]);
            acc[1] = fmaf(xr[64 + k],  w, acc[1]);
            acc[2] = fmaf(xr[128 + k], w, acc[2]);
            acc[3] = fmaf(xr[192 + k], w, acc[3]);
        }
    } else {
        for (int i = 0; i < nn; ++i)
            for (int k = 0; k < 64; ++k)
                acc[i] = fmaf(xr[i * 64 + k], W1[k * 128 + c], acc[i]);
    }
    float asc = att_s[c], adc = att_d[c];
    int head = c >> 5;
#pragma unroll
    for (int i = 0; i < 4; ++i) {
        if (i >= nn) break;
        int n = n0 + i;
        h0[(size_t)n * 128 + c] = (_Float16)acc[i];
        float s = acc[i] * asc;
        float d = acc[i] * adc;
#pragma unroll
        for (int off = 16; off >= 1; off >>= 1) {
            s += __shfl_xor(s, off);
            d += __shfl_xor(d, off);
        }
        if ((threadIdx.x & 31) == 0) {
            as1[(size_t)n * 4 + head] = s;
            ad1[(size_t)n * 4 + head] = d;
        }
    }
}

// ---------------------------------------------------------------------------
// CSR build via 256-node buckets: LDS-staged histogram + chunked binning sort
// (writes stay compact per CU -> no line-level write amplification), then a
// per-bucket finalize producing exact row_ptr / csr_src.
// Edge i: i<E -> (ei[i], ei[E+i]); i>=E -> self-loop (i-E, i-E).
// ---------------------------------------------------------------------------
__global__ void bhist_kernel(const int* __restrict__ ei, int E, int N, int NBK,
                             int* __restrict__ bhist) {
    __shared__ int h[MAXBK];
    int T = E + N;
    for (int b = threadIdx.x; b < NBK; b += 256) h[b] = 0;
    __syncthreads();
    int base = blockIdx.x * CHUNK;
#pragma unroll
    for (int k = 0; k < CHUNK; k += 256) {
        int i = base + k + threadIdx.x;
        if (i < T) {
            int dst = (i < E) ? ei[E + i] : (i - E);
            atomicAdd(&h[dst >> BK_SHIFT], 1);
        }
    }
    __syncthreads();
    for (int b = threadIdx.x; b < NBK; b += 256) {
        int v = h[b];
        if (v) atomicAdd(&bhist[b], v);
    }
}

// single block of MAXBK threads: exclusive scan of bucket counts
__global__ void bscan_kernel(const int* __restrict__ bhist, int NBK, int T,
                             int* __restrict__ bucket_base,
                             int* __restrict__ bucket_cursor) {
    __shared__ int s[MAXBK];
    int tid = threadIdx.x;
    int v = (tid < NBK) ? bhist[tid] : 0;
    s[tid] = v;
    __syncthreads();
    for (int off = 1; off < MAXBK; off <<= 1) {
        int t = (tid >= off) ? s[tid - off] : 0;
        __syncthreads();
        s[tid] += t;
        __syncthreads();
    }
    if (tid < NBK) {
        int excl = s[tid] - v;
        bucket_base[tid]   = excl;
        bucket_cursor[tid] = excl;
    }
    if (tid == 0) bucket_base[NBK] = T;
}

// chunked binning: per-block LDS histogram -> one global reservation per
// (block,bucket) -> compact pair writes into private sub-ranges.
__global__ void bin_kernel(const int* __restrict__ ei, int E, int N, int NBK,
                           int* __restrict__ bucket_cursor,
                           int2* __restrict__ binned) {
    __shared__ int cnt[MAXBK];
    __shared__ int gstart[MAXBK];
    __shared__ int cur[MAXBK];
    int T = E + N;
    for (int b = threadIdx.x; b < NBK; b += 256) { cnt[b] = 0; cur[b] = 0; }
    __syncthreads();
    int base = blockIdx.x * CHUNK;
#pragma unroll
    for (int k = 0; k < CHUNK; k += 256) {
        int i = base + k + threadIdx.x;
        if (i < T) {
            int dst = (i < E) ? ei[E + i] : (i - E);
            atomicAdd(&cnt[dst >> BK_SHIFT], 1);
        }
    }
    __syncthreads();
    for (int b = threadIdx.x; b < NBK; b += 256) {
        int c = cnt[b];
        if (c) gstart[b] = atomicAdd(&bucket_cursor[b], c);
    }
    __syncthreads();
#pragma unroll
    for (int k = 0; k < CHUNK; k += 256) {
        int i = base + k + threadIdx.x;
        if (i < T) {
            int src, dst;
            if (i < E) { src = ei[i]; dst = ei[E + i]; }
            else       { src = i - E; dst = src; }
            int b = dst >> BK_SHIFT;
            int lp = atomicAdd(&cur[b], 1);
            binned[gstart[b] + lp] = make_int2(src, dst);
        }
    }
}

// per-bucket finalize: exact per-node offsets (row_ptr) + in-bucket scatter.
// One block per bucket; all writes land in the bucket's contiguous csr range.
__global__ void csr_kernel(const int2* __restrict__ binned,
                           const int* __restrict__ bucket_base,
                           int N, int NBK, int T,
                           int* __restrict__ row_ptr,
                           int* __restrict__ csr_src) {
    __shared__ int cnt[256];
    __shared__ int loc[256];
    __shared__ int cur[256];
    int b = blockIdx.x;
    int tid = threadIdx.x;          // 256 threads
    int n0 = b << BK_SHIFT;
    int nr = N - n0; if (nr > 256) nr = 256;
    int beg = bucket_base[b], end = bucket_base[b + 1];
    cnt[tid] = 0;
    __syncthreads();
    for (int j = beg + tid; j < end; j += 256) {
        atomicAdd(&cnt[binned[j].y - n0], 1);
    }
    __syncthreads();
    int v = cnt[tid];
    loc[tid] = v;
    __syncthreads();
    for (int off = 1; off < 256; off <<= 1) {
        int t = (tid >= off) ? loc[tid - off] : 0;
        __syncthreads();
        loc[tid] += t;
        __syncthreads();
    }
    int excl = loc[tid] - v;
    cur[tid] = excl;
    if (tid < nr) row_ptr[n0 + tid] = beg + excl;
    if (b == 0 && tid == 0) row_ptr[N] = T;
    __syncthreads();
    for (int j = beg + tid; j < end; j += 256) {
        int2 p = binned[j];
        int pos = atomicAdd(&cur[p.y - n0], 1);
        csr_src[beg + pos] = p.x;
    }
}

// ---------------------------------------------------------------------------
// K6: layer-1 gather + finalize. ONE WAVE per dst node (block 256 = 4 nodes).
// 2x32-lane edge-groups; each lane loads half4 (8B) of the 256B fp16 h0 row.
// fp32 accumulate in registers; normalize + b1 + BN + ELU + dot(W2) -> h2[n].
// ---------------------------------------------------------------------------
__global__ void gather1_kernel(const int* __restrict__ row_ptr,
                               const int* __restrict__ csr_src,
                               const half4* __restrict__ h0,
                               const float* __restrict__ as1,
                               const float* __restrict__ ad1,
                               const float* __restrict__ b1,
                               const float* __restrict__ bn_gamma,
                               const float* __restrict__ bn_beta,
                               const float* __restrict__ bn_mean,
                               const float* __restrict__ bn_var,
                               const float* __restrict__ W2,
                               float* __restrict__ h2, int N) {
    int n = blockIdx.x * 4 + (threadIdx.x >> 6);
    if (n >= N) return;
    int lane = threadIdx.x & 63;
    int sub  = lane & 31;
    int grp  = lane >> 5;
    int head = sub >> 3;
    float ad = ad1[(size_t)n * 4 + head];
    int beg = row_ptr[n];
    int end = row_ptr[n + 1];
    float4 acc = make_float4(0.f, 0.f, 0.f, 0.f);
    float den = 0.f;
#pragma unroll 2
    for (int j = beg + grp; j < end; j += 2) {
        int src = csr_src[j];
        float as = as1[(size_t)src * 4 + head];
        float lg = as + ad;
        float l = fmaf(NEG_SLOPE, fminf(lg, 0.f), fmaxf(lg, 0.f));
        float w = __expf(l);
        half4 hv = h0[(size_t)src * 32 + sub];
        acc.x = fmaf(w, (float)hv.x, acc.x);
        acc.y = fmaf(w, (float)hv.y, acc.y);
        acc.z = fmaf(w, (float)hv.z, acc.z);
        acc.w = fmaf(w, (float)hv.w, acc.w);
        den += w;
    }
    acc.x += __shfl_xor(acc.x, 32);
    acc.y += __shfl_xor(acc.y, 32);
    acc.z += __shfl_xor(acc.z, 32);
    acc.w += __shfl_xor(acc.w, 32);
    den   += __shfl_xor(den, 32);
    float inv = 1.f / (den + 1e-16f);
    int c = sub * 4;
    float v0 = acc.x * inv + b1[c];
    float v1 = acc.y * inv + b1[c + 1];
    float v2 = acc.z * inv + b1[c + 2];
    float v3 = acc.w * inv + b1[c + 3];
    v0 = (v0 - bn_mean[c])     * rsqrtf(bn_var[c]     + BN_EPS) * bn_gamma[c]     + bn_beta[c];
    v1 = (v1 - bn_mean[c + 1]) * rsqrtf(bn_var[c + 1] + BN_EPS) * bn_gamma[c + 1] + bn_beta[c + 1];
    v2 = (v2 - bn_mean[c + 2]) * rsqrtf(bn_var[c + 2] + BN_EPS) * bn_gamma[c + 2] + bn_beta[c + 2];
    v3 = (v3 - bn_mean[c + 3]) * rsqrtf(bn_var[c + 3] + BN_EPS) * bn_gamma[c + 3] + bn_beta[c + 3];
    v0 = v0 > 0.f ? v0 : expm1f(v0);
    v1 = v1 > 0.f ? v1 : expm1f(v1);
    v2 = v2 > 0.f ? v2 : expm1f(v2);
    v3 = v3 > 0.f ? v3 : expm1f(v3);
    float t = v0 * W2[c] + v1 * W2[c + 1] + v2 * W2[c + 2] + v3 * W2[c + 3];
#pragma unroll
    for (int off = 16; off >= 1; off >>= 1) t += __shfl_xor(t, off);
    if (lane == 0) h2[n] = t;
}

// ---------------------------------------------------------------------------
// K7: layer-2 gather. One 64-lane wave per dst node (block 256 = 4 nodes).
// ---------------------------------------------------------------------------
__global__ void gather2_kernel(const int* __restrict__ row_ptr,
                               const int* __restrict__ csr_src,
                               const float* __restrict__ h2,
                               const float* __restrict__ att_s2,
                               const float* __restrict__ att_d2,
                               const float* __restrict__ b2,
                               float* __restrict__ out, int N) {
    int n = blockIdx.x * 4 + (threadIdx.x >> 6);
    if (n >= N) return;
    int lane = threadIdx.x & 63;
    int beg = row_ptr[n];
    int end = row_ptr[n + 1];
    float a_s = att_s2[0];
    float a_d = att_d2[0];
    float hd = h2[n];
    float num = 0.f, den = 0.f;
    for (int j = beg + lane; j < end; j += 64) {
        int src = csr_src[j];
        float hs = h2[src];
        float lg = hs * a_s + hd * a_d;
        float l = fmaf(NEG_SLOPE, fminf(lg, 0.f), fmaxf(lg, 0.f));
        float w = __expf(l);
        num += w * hs;
        den += w;
    }
#pragma unroll
    for (int off = 32; off >= 1; off >>= 1) {
        num += __shfl_xor(num, off);
        den += __shfl_xor(den, off);
    }
    if (lane == 0) out[n] = num / (den + 1e-16f) + b2[0];
}

extern "C" void kernel_launch(void* const* d_in, const int* in_sizes, int n_in,
                              void* d_out, int out_size, void* d_ws, size_t ws_size,
                              hipStream_t stream) {
    const float* x     = (const float*)d_in[0];
    const int*   ei    = (const int*)  d_in[1];
    const float* W1    = (const float*)d_in[2];
    const float* atts1 = (const float*)d_in[3];
    const float* attd1 = (const float*)d_in[4];
    const float* b1    = (const float*)d_in[5];
    const float* W2    = (const float*)d_in[6];
    const float* atts2 = (const float*)d_in[7];
    const float* attd2 = (const float*)d_in[8];
    const float* b2    = (const float*)d_in[9];
    const float* bn_g  = (const float*)d_in[10];
    const float* bn_b  = (const float*)d_in[11];
    const float* bn_m  = (const float*)d_in[12];
    const float* bn_v  = (const float*)d_in[13];

    const int N = in_sizes[0] / 64;     // 100000
    const int E = in_sizes[1] / 2;      // 1600000
    const int T = E + N;
    const int NBK = (N + 255) >> BK_SHIFT;            // 256-node buckets
    const int NCH = (T + CHUNK - 1) / CHUNK;          // binning blocks

    // workspace layout (manual alignment)
    char* p = (char*)d_ws;
    auto alloc = [&](size_t bytes, size_t align) -> void* {
        uintptr_t q = ((uintptr_t)p + align - 1) & ~(uintptr_t)(align - 1);
        p = (char*)(q + bytes);
        return (void*)q;
    };
    _Float16* h0       = (_Float16*)alloc((size_t)N * 128 * 2, 16);
    float* as1         = (float*)alloc((size_t)N * 4 * 4, 16);
    float* ad1         = (float*)alloc((size_t)N * 4 * 4, 16);
    float* h2          = (float*)alloc((size_t)N * 4, 16);
    int*   row_ptr     = (int*)alloc((size_t)(N + 1) * 4, 16);
    int*   csr_src     = (int*)alloc((size_t)T * 4, 16);
    int*   bhist       = (int*)alloc((size_t)MAXBK * 4, 16);
    int*   bucket_base = (int*)alloc((size_t)(MAXBK + 1) * 4, 16);
    int*   bucket_cur  = (int*)alloc((size_t)MAXBK * 4, 16);
    int2*  binned      = (int2*)alloc((size_t)T * 8, 16);

    hipMemsetAsync(bhist, 0, (size_t)MAXBK * sizeof(int), stream);

    bhist_kernel<<<NCH, 256, 0, stream>>>(ei, E, N, NBK, bhist);
    bscan_kernel<<<1, MAXBK, 0, stream>>>(bhist, NBK, T, bucket_base, bucket_cur);
    bin_kernel<<<NCH, 256, 0, stream>>>(ei, E, N, NBK, bucket_cur, binned);
    csr_kernel<<<NBK, 256, 0, stream>>>(binned, bucket_base, N, NBK, T,
                                        row_ptr, csr_src);

    gemm1_kernel<<<(N + 7) / 8, 256, 0, stream>>>(
        x, W1, atts1, attd1, h0, as1, ad1, N);

    gather1_kernel<<<(N + 3) / 4, 256, 0, stream>>>(
        row_ptr, csr_src, (const half4*)h0, as1, ad1, b1, bn_g, bn_b, bn_m, bn_v,
        W2, h2, N);

    gather2_kernel<<<(N + 3) / 4, 256, 0, stream>>>(
        row_ptr, csr_src, h2, atts2, attd2, b2, (float*)d_out, N);
}